// Round 7
// baseline (258.457 us; speedup 1.0000x reference)
//
#include <hip/hip_runtime.h>
#include <math.h>

#define B_DIM 8
#define T_DIM 512
#define H_DIM 768
#define NTOK 511       // T - 1
#define NLAY 9         // 13 - LAYER_START
#define LAYER_START 4
#define NBAND 35       // pairs with |i-j| <= 4 (all that's needed)
#define NCHUNK 64      // stage-C token chunks (8 tokens each)

// banded Gram index: pair (lo, lo+d), d<=4 -> BOFF(d)+lo
#define BOFF(d) ((d)*9 - (d) * ((d)-1) / 2)

// Inter-stage buffers. Module globals (never touch d_ws). Every element read
// by a later stage is written earlier in the same call -> poison-safe.
__device__ float g_gram[B_DIM * T_DIM * NBAND];   // [b][t(512)][35]  573 KB
__device__ float g_w[B_DIM * NTOK * NLAY];        // var*alpha/csum   147 KB
__device__ float g_var[B_DIM * NTOK];             // var_tok           16 KB
__device__ float g_part[B_DIM * NCHUNK * H_DIM];  // C partials       1.6 MB

// ---- DPP cross-lane (VALU pipe, no DS) ----
template <int CTRL>
__device__ __forceinline__ float dpp_mov(float x) {
  return __builtin_bit_cast(
      float, __builtin_amdgcn_update_dpp(0, __builtin_bit_cast(int, x), CTRL,
                                         0xF, 0xF, true));
}
// 64-lane sum; total lands in lane 63.
__device__ __forceinline__ float wave_sum_dpp(float x) {
  x += dpp_mov<0x111>(x);  // row_shr:1
  x += dpp_mov<0x112>(x);  // row_shr:2
  x += dpp_mov<0x114>(x);  // row_shr:4
  x += dpp_mov<0x118>(x);  // row_shr:8
  x += dpp_mov<0x142>(x);  // row_bcast:15
  x += dpp_mov<0x143>(x);  // row_bcast:31
  return x;
}

// =========================== stage A: Gram ===========================
// grid (128, 8) x 256 thr; 4 waves/block, one token per wave.
// Segmented over H so live set ~(36 v + 35 g + temps) fits the 128-VGPR cap
// of (256,4) with no spill; pure streaming, no tail.
__global__ __launch_bounds__(256, 4) void gram_k(const float* __restrict__ ahs) {
  const int chunk = blockIdx.x;
  const int b = blockIdx.y;
  const int wave = threadIdx.x >> 6;
  const int lane = threadIdx.x & 63;
  const int t_raw = chunk * 4 + wave;                 // 0..511
  const int t = (t_raw < NTOK) ? t_raw : (NTOK - 1);  // clamp loads

  __shared__ float sGall[4][NBAND];

  const size_t LSTR = (size_t)B_DIM * T_DIM * H_DIM;
  const float* lay0 =
      ahs + (size_t)LAYER_START * LSTR + ((size_t)b * T_DIM + t) * H_DIM;

  float g[NBAND];
#pragma unroll
  for (int p = 0; p < NBAND; ++p) g[p] = 0.f;

#pragma unroll 1
  for (int s = 0; s < 3; ++s) {
    const float* p0 = lay0 + s * 256 + lane * 4;
    float4 vs[NLAY];
#pragma unroll
    for (int l = 0; l < NLAY; ++l)
      vs[l] = *reinterpret_cast<const float4*>(p0 + (size_t)l * LSTR);
#pragma unroll
    for (int d = 0; d <= 4; ++d) {
#pragma unroll
      for (int i = 0; i + d < NLAY; ++i) {
        const float4 x = vs[i], y = vs[i + d];
        g[BOFF(d) + i] += x.x * y.x + x.y * y.y + x.z * y.z + x.w * y.w;
      }
    }
  }

#pragma unroll
  for (int p = 0; p < NBAND; ++p) g[p] = wave_sum_dpp(g[p]);

  if (lane == 63) {
#pragma unroll
    for (int p = 0; p < NBAND; ++p) sGall[wave][p] = g[p];
  }
  __syncthreads();

  // coalesced store: 140 consecutive floats per block (slot t=511 unused)
  const int i = threadIdx.x;
  if (i < 4 * NBAND) {
    const int w = i / NBAND;
    const int p = i - w * NBAND;
    const int tr = chunk * 4 + w;
    g_gram[((size_t)(b * T_DIM + tr)) * NBAND + p] = sGall[w][p];
  }
}

// ======================= stage B: per-token tail ======================
// One lane per token. Cholesky-of-Gram == QR's R up to row signs (cancel).
template <int K>
__device__ __forceinline__ void chol_one(const float* __restrict__ row,
                                         float& A_out, float& N_out) {
  constexpr int nl = (K >= 2) ? 2 : 0;
  constexpr int nr = ((NLAY - 1 - K) < 2) ? (NLAY - 1 - K) : 2;
  constexpr int m = nl + nr + 1;  // 3..5, self row last

  struct Map {
    static constexpr int rowf(int i) {
      return (i < nl) ? (K - 2 + i) : ((i < nl + nr) ? (K + 1 + i - nl) : K);
    }
  };
  auto GK = [&](int i, int j) -> float {
    const int a = Map::rowf(i), c = Map::rowf(j);
    const int lo = a < c ? a : c;
    const int d = (a < c ? c : a) - lo;  // 0..4 (window span <= 4)
    return row[d * 9 - d * (d - 1) / 2 + lo];
  };

  float R[5][5];
#pragma unroll
  for (int j = 0; j < 5; ++j)
#pragma unroll
    for (int i = 0; i < 5; ++i) R[i][j] = 0.f;

#pragma unroll
  for (int j = 0; j < 5; ++j) {
    if (j < m) {
#pragma unroll
      for (int i = 0; i < 5; ++i) {
        if (i < j) {
          float s = GK(i, j);
#pragma unroll
          for (int p = 0; p < 4; ++p)
            if (p < i) s -= R[p][i] * R[p][j];
          R[i][j] = s / R[i][i];
        }
      }
      float sjj = GK(j, j);
#pragma unroll
      for (int p = 0; p < 4; ++p)
        if (p < j) sjj -= R[p][j] * R[p][j];
      R[j][j] = sqrtf(fmaxf(sjj, 0.f));
    }
  }

  float r[5];
#pragma unroll
  for (int i = 0; i < 5; ++i) r[i] = R[i][m - 1];

  float rowmean[4] = {0.f, 0.f, 0.f, 0.f};
#pragma unroll
  for (int j = 0; j < 4; ++j) {
    if (j < m - 1) {
      float cn = 0.f;
#pragma unroll
      for (int i = 0; i < 4; ++i)
        if (i <= j) cn += R[i][j] * R[i][j];
      cn = fmaxf(sqrtf(cn), 1e-12f);
      const float inv = 1.f / cn;
#pragma unroll
      for (int i = 0; i < 4; ++i)
        if (i < m - 1) rowmean[i] += R[i][j] * inv;
    }
  }

  constexpr float inv_m1 = 1.f / (float)(m - 1);
  float dotv = 0.f, nrm2 = 0.f;
#pragma unroll
  for (int i = 0; i < 4; ++i) {
    if (i < m - 1) {
      dotv += (rowmean[i] * inv_m1) * r[i];
      nrm2 += r[i] * r[i];
    }
  }
  const float align_raw = dotv / sqrtf(nrm2);
  A_out = 1.f / (align_raw * (float)m * 2.f);
  const float rlast = r[m - 1];
  N_out = fabsf(rlast) / sqrtf(nrm2 + rlast * rlast);
}

__global__ __launch_bounds__(64) void tail_k() {
  const int tid = threadIdx.x;
  const int tok = blockIdx.x * 64 + tid;
  const bool valid = (tok < B_DIM * NTOK);
  const int tk = valid ? tok : 0;
  const int b = tk / NTOK;
  const int t = tk - b * NTOK;

  __shared__ float sB[64][NBAND + 2];  // stride 37: conflict-free

  const float* gp = g_gram + ((size_t)(b * T_DIM + t)) * NBAND;
#pragma unroll
  for (int p = 0; p < NBAND; ++p) sB[tid][p] = gp[p];
  const float* row = &sB[tid][0];

  float al[NLAY], nv[NLAY];
  chol_one<0>(row, al[0], nv[0]);
  chol_one<1>(row, al[1], nv[1]);
  chol_one<2>(row, al[2], nv[2]);
  chol_one<3>(row, al[3], nv[3]);
  chol_one<4>(row, al[4], nv[4]);
  chol_one<5>(row, al[5], nv[5]);
  chol_one<6>(row, al[6], nv[6]);
  chol_one<7>(row, al[7], nv[7]);
  chol_one<8>(row, al[8], nv[8]);

  float asum = 0.f, nsum = 0.f;
#pragma unroll
  for (int l = 0; l < NLAY; ++l) { asum += al[l]; nsum += nv[l]; }
  float alpha[NLAY];
  float csum = 0.f;
#pragma unroll
  for (int l = 0; l < NLAY; ++l) {
    alpha[l] = al[l] / asum + nv[l] / nsum;
    csum += alpha[l];
  }
  const float inv_csum = 1.f / csum;

  float sims[NLAY - 1];
  float smean = 0.f;
#pragma unroll
  for (int j = 0; j < NLAY - 1; ++j) {
    const float num = row[BOFF(1) + j];
    const float den = fmaxf(sqrtf(row[j]) * sqrtf(row[j + 1]), 1e-8f);
    sims[j] = num / den;
    smean += sims[j];
  }
  smean *= (1.f / 8.f);
  float var = 0.f;
#pragma unroll
  for (int j = 0; j < NLAY - 1; ++j) {
    const float d = sims[j] - smean;
    var += d * d;
  }
  var *= (1.f / 7.f);

  if (valid) {
#pragma unroll
    for (int l = 0; l < NLAY; ++l)
      g_w[(size_t)tok * NLAY + l] = var * alpha[l] * inv_csum;
    g_var[tok] = var;
  }
}

// ==================== stage C: weighted sum partials ==================
// grid (NCHUNK, B_DIM) x 192 thr; each thread owns 4 h's; 8 tokens/block.
__global__ __launch_bounds__(192) void wsum_k(const float* __restrict__ ahs) {
  const int c = blockIdx.x;
  const int b = blockIdx.y;
  const int h4 = threadIdx.x;  // 0..191 -> h = h4*4
  const size_t LSTR = (size_t)B_DIM * T_DIM * H_DIM;

  float4 acc;
  acc.x = 0.f; acc.y = 0.f; acc.z = 0.f; acc.w = 0.f;

#pragma unroll 1
  for (int tt = 0; tt < 8; ++tt) {
    const int t = c * 8 + tt;
    if (t >= NTOK) break;
    const float* wp = g_w + ((size_t)(b * NTOK + t)) * NLAY;  // uniform
    const float* vbase = ahs + (size_t)LAYER_START * LSTR +
                         ((size_t)b * T_DIM + t) * H_DIM + h4 * 4;
#pragma unroll
    for (int l = 0; l < NLAY; ++l) {
      const float wl = wp[l];
      const float4 vv = *reinterpret_cast<const float4*>(vbase + (size_t)l * LSTR);
      acc.x += wl * vv.x;
      acc.y += wl * vv.y;
      acc.z += wl * vv.z;
      acc.w += wl * vv.w;
    }
  }
  *reinterpret_cast<float4*>(g_part + ((size_t)(b * NCHUNK + c)) * H_DIM +
                             h4 * 4) = acc;
}

// ===================== stage D: reduce + normalize ====================
__global__ __launch_bounds__(256) void fin_k(float* __restrict__ out) {
  const int b = blockIdx.y;
  const int h = blockIdx.x * 256 + threadIdx.x;

  float acc = 0.f;
#pragma unroll 8
  for (int cc = 0; cc < NCHUNK; ++cc)
    acc += g_part[((size_t)(b * NCHUNK + cc)) * H_DIM + h];

  float sv = 0.f;  // uniform address stream -> scalar loads
#pragma unroll 8
  for (int t = 0; t < NTOK; ++t) sv += g_var[b * NTOK + t];

  out[b * H_DIM + h] = acc / sv;
}

extern "C" void kernel_launch(void* const* d_in, const int* in_sizes, int n_in,
                              void* d_out, int out_size, void* d_ws, size_t ws_size,
                              hipStream_t stream) {
  const float* ahs = (const float*)d_in[0];
  // d_in[1] = attention_mask: unused by the reference computation
  float* out = (float*)d_out;
  (void)d_ws; (void)ws_size;

  gram_k<<<dim3(T_DIM / 4, B_DIM), dim3(256), 0, stream>>>(ahs);
  tail_k<<<dim3((B_DIM * NTOK + 63) / 64), dim3(64), 0, stream>>>();
  wsum_k<<<dim3(NCHUNK, B_DIM), dim3(192), 0, stream>>>(ahs);
  fin_k<<<dim3(3, B_DIM), dim3(256), 0, stream>>>(out);
}